// Round 1
// baseline (1547.558 us; speedup 1.0000x reference)
//
#include <hip/hip_runtime.h>
#include <hip/hip_bf16.h>

#define L_ 4096
#define CCH 256

// ---------------- K1: LayerNorm over C + branch scatter ----------------
// x: [4][256][4096] -> stacked: [16][4096][64], stacked[br*4+b][l][j] = xn[b][l][(224+64br+j)&255]
__global__ __launch_bounds__(256) void k1_ln_scatter(
    const float* __restrict__ x, const float* __restrict__ g,
    const float* __restrict__ bb, float* __restrict__ stacked) {
  int b = blockIdx.y;
  int l = blockIdx.x * 256 + threadIdx.x;
  const float* xb = x + (size_t)b * CCH * L_ + l;
  float sum = 0.f, sq = 0.f;
  for (int c = 0; c < CCH; ++c) {
    float v = xb[(size_t)c * L_];
    sum += v; sq += v * v;
  }
  float mean = sum * (1.0f / CCH);
  float var = sq * (1.0f / CCH) - mean * mean;
  float rstd = rsqrtf(var + 1e-5f);
  for (int c = 0; c < CCH; ++c) {
    float v = (xb[(size_t)c * L_] - mean) * rstd * g[c] + bb[c];
    int gi = (c + 32) & 255;
    int br = gi >> 6, j = gi & 63;
    int n = br * 4 + b;
    stacked[((size_t)n * L_ + l) * 64 + j] = v;
  }
}

// ---------------- K2: in_proj GEMM  xz = stacked @ W^T ----------------
// stacked [16][L][64], W [256][64] -> xi [16][L][128], z [16][L][128]
__global__ __launch_bounds__(256) void k2_inproj(
    const float* __restrict__ stacked, const float* __restrict__ w,
    float* __restrict__ xi, float* __restrict__ z) {
  int n = blockIdx.z, l0 = blockIdx.x * 64, k0 = blockIdx.y * 64;
  __shared__ float As[64][68];
  __shared__ float Ws[64][68];
  int t = threadIdx.y * 16 + threadIdx.x;
  for (int e = t; e < 4096; e += 256) {
    int r = e >> 6, c = e & 63;
    As[r][c] = stacked[((size_t)n * L_ + l0 + r) * 64 + c];
    Ws[r][c] = w[(k0 + r) * 64 + c];
  }
  __syncthreads();
  float acc[4][4] = {};
  for (int jj = 0; jj < 16; ++jj) {
    float4 a[4], bm[4];
#pragma unroll
    for (int i = 0; i < 4; i++) a[i] = *reinterpret_cast<const float4*>(&As[threadIdx.y * 4 + i][jj * 4]);
#pragma unroll
    for (int i = 0; i < 4; i++) bm[i] = *reinterpret_cast<const float4*>(&Ws[threadIdx.x * 4 + i][jj * 4]);
#pragma unroll
    for (int i = 0; i < 4; i++)
#pragma unroll
      for (int kk = 0; kk < 4; kk++)
        acc[i][kk] += a[i].x * bm[kk].x + a[i].y * bm[kk].y + a[i].z * bm[kk].z + a[i].w * bm[kk].w;
  }
  int kb = k0 + threadIdx.x * 4;
  float* dst = (kb < 128) ? xi : z;
  int kd = (kb < 128) ? kb : kb - 128;
#pragma unroll
  for (int i = 0; i < 4; i++) {
    int l = l0 + threadIdx.y * 4 + i;
    float4 v = make_float4(acc[i][0], acc[i][1], acc[i][2], acc[i][3]);
    *reinterpret_cast<float4*>(&dst[((size_t)n * L_ + l) * 128 + kd]) = v;
  }
}

// ---------------- K3: causal conv1d + silu + x_proj + dt_proj + softplus ----------------
__global__ __launch_bounds__(128) void k3_conv_xproj(
    const float* __restrict__ xi, const float* __restrict__ cw,
    const float* __restrict__ cb, const float* __restrict__ xw,
    const float* __restrict__ dtw, const float* __restrict__ dtb,
    float* __restrict__ u, float* __restrict__ delta,
    float* __restrict__ Bc, float* __restrict__ Cc) {
  int n = blockIdx.y, l0 = blockIdx.x * 128, t = threadIdx.x;
  __shared__ float xt[131][129];  // +1 pad: lanes stride 129 floats -> conflict-free
  for (int e = t; e < 131 * 128; e += 128) {
    int r = e >> 7, c = e & 127;
    int gl = l0 - 3 + r;
    xt[r][c] = (gl >= 0) ? xi[((size_t)n * L_ + gl) * 128 + c] : 0.f;
  }
  __syncthreads();
  int l = l0 + t;
  size_t base = (size_t)n * L_ + l;
  float acc36[36] = {};
  for (int d = 0; d < 128; ++d) {
    float s = cb[d];
#pragma unroll
    for (int k = 0; k < 4; ++k) s += xt[t + k][d] * cw[d * 4 + k];
    float uv = s / (1.f + __expf(-s));  // silu
    u[base * 128 + d] = uv;
#pragma unroll
    for (int r = 0; r < 36; ++r) acc36[r] += uv * xw[r * 128 + d];
  }
#pragma unroll
  for (int s16 = 0; s16 < 16; ++s16) {
    Bc[base * 16 + s16] = acc36[4 + s16];
    Cc[base * 16 + s16] = acc36[20 + s16];
  }
  for (int d = 0; d < 128; ++d) {
    float dv = dtb[d];
#pragma unroll
    for (int r = 0; r < 4; ++r) dv += acc36[r] * dtw[d * 4 + r];
    delta[base * 128 + d] = (dv > 20.f) ? dv : log1pf(__expf(dv));  // softplus
  }
}

// ---------------- K4: selective scan (sequential over L) ----------------
// thread = (n, d, s): h_{l} = exp(delta*A)*h_{l-1} + delta*u*B ; y = sum_s h*C
__global__ __launch_bounds__(64) void k4_scan(
    const float* __restrict__ delta, const float* __restrict__ u,
    const float* __restrict__ Bc, const float* __restrict__ Cc,
    const float* __restrict__ A_log, float* __restrict__ y) {
  int bid = blockIdx.x;
  int n = bid >> 5, d0 = (bid & 31) * 4;
  int lane = threadIdx.x;
  int dl = lane >> 4, s = lane & 15;
  int d = d0 + dl;
  float A = -expf(A_log[d * 16 + s]);
  const float* dp = delta + (size_t)n * L_ * 128 + d;
  const float* up = u + (size_t)n * L_ * 128 + d;
  const float* bp = Bc + (size_t)n * L_ * 16 + s;
  const float* cp = Cc + (size_t)n * L_ * 16 + s;
  float* yp = y + (size_t)n * L_ * 128 + d;
  float h = 0.f;
  float dv = dp[0], uv = up[0], bv = bp[0], cv = cp[0];
  for (int l = 0; l < L_; ++l) {
    int ln = (l + 1 < L_) ? l + 1 : l;
    float dv2 = dp[(size_t)ln * 128];
    float uv2 = up[(size_t)ln * 128];
    float bv2 = bp[ln * 16];
    float cv2 = cp[ln * 16];
    float dA = __expf(dv * A);
    h = fmaf(dA, h, dv * uv * bv);
    float p = h * cv;
    p += __shfl_xor(p, 1);
    p += __shfl_xor(p, 2);
    p += __shfl_xor(p, 4);
    p += __shfl_xor(p, 8);
    if (s == 0) yp[(size_t)l * 128] = p;
    dv = dv2; uv = uv2; bv = bv2; cv = cv2;
  }
}

// ---------------- K5: gate + out_proj GEMM + skip ----------------
// yy = (y + u*D) * silu(z); ym = yy @ out_w^T + skip*stacked   -> [16][L][64]
__global__ __launch_bounds__(256) void k5_gate_outproj(
    const float* __restrict__ y, const float* __restrict__ u,
    const float* __restrict__ z, const float* __restrict__ Dv,
    const float* __restrict__ ow, const float* __restrict__ stacked,
    const float* __restrict__ skip, float* __restrict__ ym) {
  int n = blockIdx.y, l0 = blockIdx.x * 64;
  __shared__ float As[64][132];
  __shared__ float Ws[64][132];
  int t = threadIdx.y * 16 + threadIdx.x;
  for (int e = t; e < 64 * 128; e += 256) {
    int r = e >> 7, c = e & 127;
    size_t idx = ((size_t)n * L_ + l0 + r) * 128 + c;
    float zz = z[idx];
    As[r][c] = (y[idx] + u[idx] * Dv[c]) * (zz / (1.f + __expf(-zz)));
    Ws[r][c] = ow[(size_t)r * 128 + c];
  }
  __syncthreads();
  float acc[4][4] = {};
  for (int jj = 0; jj < 32; ++jj) {
    float4 a[4], bm[4];
#pragma unroll
    for (int i = 0; i < 4; i++) a[i] = *reinterpret_cast<const float4*>(&As[threadIdx.y * 4 + i][jj * 4]);
#pragma unroll
    for (int i = 0; i < 4; i++) bm[i] = *reinterpret_cast<const float4*>(&Ws[threadIdx.x * 4 + i][jj * 4]);
#pragma unroll
    for (int i = 0; i < 4; i++)
#pragma unroll
      for (int kk = 0; kk < 4; kk++)
        acc[i][kk] += a[i].x * bm[kk].x + a[i].y * bm[kk].y + a[i].z * bm[kk].z + a[i].w * bm[kk].w;
  }
  float sk = skip[0];
#pragma unroll
  for (int i = 0; i < 4; i++) {
    int l = l0 + threadIdx.y * 4 + i;
    const float4 st = *reinterpret_cast<const float4*>(&stacked[((size_t)n * L_ + l) * 64 + threadIdx.x * 4]);
    float4 v = make_float4(acc[i][0] + sk * st.x, acc[i][1] + sk * st.y,
                           acc[i][2] + sk * st.z, acc[i][3] + sk * st.w);
    *reinterpret_cast<float4*>(&ym[((size_t)n * L_ + l) * 64 + threadIdx.x * 4]) = v;
  }
}

// ---------------- K6a: inverse shuffle + LayerNorm2 ----------------
__global__ __launch_bounds__(256) void k6a_ln2(
    const float* __restrict__ ym, const float* __restrict__ g,
    const float* __restrict__ bb, float* __restrict__ xmn) {
  int b = blockIdx.y;
  int l = blockIdx.x * 256 + threadIdx.x;
  float sum = 0.f, sq = 0.f;
  for (int c = 0; c < 256; ++c) {
    int gi = (c + 32) & 255;
    int br = gi >> 6, j = gi & 63;
    float v = ym[((size_t)(br * 4 + b) * L_ + l) * 64 + j];
    sum += v; sq += v * v;
  }
  float mean = sum * (1.0f / 256), rstd = rsqrtf(sq * (1.0f / 256) - mean * mean + 1e-5f);
  for (int c = 0; c < 256; ++c) {
    int gi = (c + 32) & 255;
    int br = gi >> 6, j = gi & 63;
    float v = ym[((size_t)(br * 4 + b) * L_ + l) * 64 + j];
    xmn[((size_t)b * L_ + l) * 256 + c] = (v - mean) * rstd * g[c] + bb[c];
  }
}

// ---------------- K6b: final 256x256 GEMM + bias + transpose store ----------------
__global__ __launch_bounds__(256) void k6b_proj(
    const float* __restrict__ xmn, const float* __restrict__ pw,
    const float* __restrict__ pb, float* __restrict__ out) {
  int b = blockIdx.z, k0 = blockIdx.y * 64, l0 = blockIdx.x * 64;
  __shared__ float As[64][68];
  __shared__ float Ws[64][68];
  int t = threadIdx.y * 16 + threadIdx.x;
  float acc[4][4] = {};
  for (int cc = 0; cc < 4; ++cc) {
    __syncthreads();
    for (int e = t; e < 4096; e += 256) {
      int r = e >> 6, c = e & 63;
      As[r][c] = xmn[((size_t)b * L_ + l0 + r) * 256 + cc * 64 + c];
      Ws[r][c] = pw[(k0 + r) * 256 + cc * 64 + c];
    }
    __syncthreads();
    for (int jj = 0; jj < 16; ++jj) {
      float4 a[4], bm[4];
#pragma unroll
      for (int i = 0; i < 4; i++) a[i] = *reinterpret_cast<const float4*>(&As[threadIdx.y * 4 + i][jj * 4]);
#pragma unroll
      for (int i = 0; i < 4; i++) bm[i] = *reinterpret_cast<const float4*>(&Ws[threadIdx.x * 4 + i][jj * 4]);
#pragma unroll
      for (int i = 0; i < 4; i++)
#pragma unroll
        for (int kk = 0; kk < 4; kk++)
          acc[i][kk] += a[i].x * bm[kk].x + a[i].y * bm[kk].y + a[i].z * bm[kk].z + a[i].w * bm[kk].w;
    }
  }
#pragma unroll
  for (int kk = 0; kk < 4; kk++) {
    int k = k0 + threadIdx.x * 4 + kk;
    float pbv = pb[k];
#pragma unroll
    for (int i = 0; i < 4; i++) {
      int l = l0 + threadIdx.y * 4 + i;
      out[((size_t)b * 256 + k) * L_ + l] = acc[i][kk] + pbv;
    }
  }
}

extern "C" void kernel_launch(void* const* d_in, const int* in_sizes, int n_in,
                              void* d_out, int out_size, void* d_ws, size_t ws_size,
                              hipStream_t stream) {
  const float* x        = (const float*)d_in[0];
  const float* norm_g   = (const float*)d_in[1];
  const float* norm_b   = (const float*)d_in[2];
  const float* skip     = (const float*)d_in[3];
  const float* proj_w   = (const float*)d_in[4];
  const float* proj_b   = (const float*)d_in[5];
  const float* in_proj_w= (const float*)d_in[6];
  const float* conv_w   = (const float*)d_in[7];
  const float* conv_b   = (const float*)d_in[8];
  const float* x_proj_w = (const float*)d_in[9];
  const float* dt_w     = (const float*)d_in[10];
  const float* dt_b     = (const float*)d_in[11];
  const float* A_log    = (const float*)d_in[12];
  const float* Dv       = (const float*)d_in[13];
  const float* out_w    = (const float*)d_in[14];
  float* out = (float*)d_out;
  float* ws  = (float*)d_ws;

  // workspace layout (floats)
  float* stacked = ws;                    // 16*4096*64   = 4,194,304
  float* xi      = ws + 4194304;          // 16*4096*128  = 8,388,608  (reused as y after K3)
  float* z       = ws + 12582912;         // 8,388,608
  float* u       = ws + 20971520;         // 8,388,608
  float* delta   = ws + 29360128;         // 8,388,608   (reused: ym + xmn after K4)
  float* Bc      = ws + 37748736;         // 1,048,576
  float* Cc      = ws + 38797312;         // 1,048,576
  float* ym      = delta;                 // 4,194,304
  float* xmn     = delta + 4194304;       // 4,194,304

  k1_ln_scatter<<<dim3(16, 4), 256, 0, stream>>>(x, norm_g, norm_b, stacked);
  k2_inproj<<<dim3(64, 4, 16), dim3(16, 16), 0, stream>>>(stacked, in_proj_w, xi, z);
  k3_conv_xproj<<<dim3(32, 16), 128, 0, stream>>>(xi, conv_w, conv_b, x_proj_w,
                                                  dt_w, dt_b, u, delta, Bc, Cc);
  k4_scan<<<512, 64, 0, stream>>>(delta, u, Bc, Cc, A_log, xi /*y*/);
  k5_gate_outproj<<<dim3(64, 16), dim3(16, 16), 0, stream>>>(xi /*y*/, u, z, Dv,
                                                             out_w, stacked, skip, ym);
  k6a_ln2<<<dim3(16, 4), 256, 0, stream>>>(ym, norm_g, norm_b, xmn);
  k6b_proj<<<dim3(64, 4, 4), dim3(16, 16), 0, stream>>>(xmn, proj_w, proj_b, out);
}

// Round 3
// 572.008 us; speedup vs baseline: 2.7055x; 2.7055x over previous
//
#include <hip/hip_runtime.h>
#include <hip/hip_bf16.h>

#define L_ 4096
#define CCH 256
#define CH 64     // scan chunk length
#define NC 64     // number of chunks (L_/CH)

// ---------------- K1: LayerNorm over C + branch scatter ----------------
// x: [4][256][4096] -> stacked: [16][4096][64], stacked[br*4+b][l][j] = xn[b][l][(224+64br+j)&255]
__global__ __launch_bounds__(256) void k1_ln_scatter(
    const float* __restrict__ x, const float* __restrict__ g,
    const float* __restrict__ bb, float* __restrict__ stacked) {
  int b = blockIdx.y;
  int l = blockIdx.x * 256 + threadIdx.x;
  const float* xb = x + (size_t)b * CCH * L_ + l;
  float sum = 0.f, sq = 0.f;
  for (int c = 0; c < CCH; ++c) {
    float v = xb[(size_t)c * L_];
    sum += v; sq += v * v;
  }
  float mean = sum * (1.0f / CCH);
  float var = sq * (1.0f / CCH) - mean * mean;
  float rstd = rsqrtf(var + 1e-5f);
  for (int c = 0; c < CCH; ++c) {
    float v = (xb[(size_t)c * L_] - mean) * rstd * g[c] + bb[c];
    int gi = (c + 32) & 255;
    int br = gi >> 6, j = gi & 63;
    int n = br * 4 + b;
    stacked[((size_t)n * L_ + l) * 64 + j] = v;
  }
}

// ---------------- K2: in_proj GEMM  xz = stacked @ W^T ----------------
__global__ __launch_bounds__(256) void k2_inproj(
    const float* __restrict__ stacked, const float* __restrict__ w,
    float* __restrict__ xi, float* __restrict__ z) {
  int n = blockIdx.z, l0 = blockIdx.x * 64, k0 = blockIdx.y * 64;
  __shared__ float As[64][68];
  __shared__ float Ws[64][68];
  int t = threadIdx.y * 16 + threadIdx.x;
  for (int e = t; e < 4096; e += 256) {
    int r = e >> 6, c = e & 63;
    As[r][c] = stacked[((size_t)n * L_ + l0 + r) * 64 + c];
    Ws[r][c] = w[(k0 + r) * 64 + c];
  }
  __syncthreads();
  float acc[4][4] = {};
  for (int jj = 0; jj < 16; ++jj) {
    float4 a[4], bm[4];
#pragma unroll
    for (int i = 0; i < 4; i++) a[i] = *reinterpret_cast<const float4*>(&As[threadIdx.y * 4 + i][jj * 4]);
#pragma unroll
    for (int i = 0; i < 4; i++) bm[i] = *reinterpret_cast<const float4*>(&Ws[threadIdx.x * 4 + i][jj * 4]);
#pragma unroll
    for (int i = 0; i < 4; i++)
#pragma unroll
      for (int kk = 0; kk < 4; kk++)
        acc[i][kk] += a[i].x * bm[kk].x + a[i].y * bm[kk].y + a[i].z * bm[kk].z + a[i].w * bm[kk].w;
  }
  int kb = k0 + threadIdx.x * 4;
  float* dst = (kb < 128) ? xi : z;
  int kd = (kb < 128) ? kb : kb - 128;
#pragma unroll
  for (int i = 0; i < 4; i++) {
    int l = l0 + threadIdx.y * 4 + i;
    float4 v = make_float4(acc[i][0], acc[i][1], acc[i][2], acc[i][3]);
    *reinterpret_cast<float4*>(&dst[((size_t)n * L_ + l) * 128 + kd]) = v;
  }
}

// ---------------- K3: causal conv1d + silu + x_proj + dt_proj + softplus ----------------
__global__ __launch_bounds__(128) void k3_conv_xproj(
    const float* __restrict__ xi, const float* __restrict__ cw,
    const float* __restrict__ cb, const float* __restrict__ xw,
    const float* __restrict__ dtw, const float* __restrict__ dtb,
    float* __restrict__ u, float* __restrict__ delta,
    float* __restrict__ Bc, float* __restrict__ Cc) {
  int n = blockIdx.y, l0 = blockIdx.x * 128, t = threadIdx.x;
  __shared__ float xt[131][129];
  for (int e = t; e < 131 * 128; e += 128) {
    int r = e >> 7, c = e & 127;
    int gl = l0 - 3 + r;
    xt[r][c] = (gl >= 0) ? xi[((size_t)n * L_ + gl) * 128 + c] : 0.f;
  }
  __syncthreads();
  int l = l0 + t;
  size_t base = (size_t)n * L_ + l;
  float acc36[36] = {};
  for (int d = 0; d < 128; ++d) {
    float s = cb[d];
#pragma unroll
    for (int k = 0; k < 4; ++k) s += xt[t + k][d] * cw[d * 4 + k];
    float uv = s / (1.f + __expf(-s));  // silu
    u[base * 128 + d] = uv;
#pragma unroll
    for (int r = 0; r < 36; ++r) acc36[r] += uv * xw[r * 128 + d];
  }
#pragma unroll
  for (int s16 = 0; s16 < 16; ++s16) {
    Bc[base * 16 + s16] = acc36[4 + s16];
    Cc[base * 16 + s16] = acc36[20 + s16];
  }
  for (int d = 0; d < 128; ++d) {
    float dv = dtb[d];
#pragma unroll
    for (int r = 0; r < 4; ++r) dv += acc36[r] * dtw[d * 4 + r];
    delta[base * 128 + d] = (dv > 20.f) ? dv : log1pf(__expf(dv));
  }
}

// ---------------- K4a: per-chunk local scan (h from 0) + chunk delta-sum ----------------
// thread = (n, chunk, d); holds all 16 states in registers.
__global__ __launch_bounds__(128) void k4a_chunk(
    const float* __restrict__ delta, const float* __restrict__ u,
    const float* __restrict__ Bc, const float* __restrict__ A_log,
    float* __restrict__ hend, float* __restrict__ Sdelta) {
  int c = blockIdx.x, n = blockIdx.y, d = threadIdx.x;
  __shared__ float Bs[CH * 16];
  const float* bsrc = Bc + ((size_t)n * L_ + c * CH) * 16;
  for (int e = d; e < CH * 16; e += 128) Bs[e] = bsrc[e];
  float A[16];
#pragma unroll
  for (int s = 0; s < 16; ++s) A[s] = -__expf(A_log[d * 16 + s]);
  __syncthreads();

  const float* dp = delta + ((size_t)n * L_ + c * CH) * 128 + d;
  const float* up = u + ((size_t)n * L_ + c * CH) * 128 + d;
  float h[16] = {};
  float sd = 0.f;
  float dv = dp[0], uv = up[0];
  for (int l = 0; l < CH; ++l) {
    int ln = (l + 1 < CH) ? l + 1 : l;
    float dvn = dp[(size_t)ln * 128];
    float uvn = up[(size_t)ln * 128];
    sd += dv;
    float du = dv * uv;
    float bsv[16];
    *reinterpret_cast<float4*>(&bsv[0])  = *reinterpret_cast<const float4*>(&Bs[l * 16 + 0]);
    *reinterpret_cast<float4*>(&bsv[4])  = *reinterpret_cast<const float4*>(&Bs[l * 16 + 4]);
    *reinterpret_cast<float4*>(&bsv[8])  = *reinterpret_cast<const float4*>(&Bs[l * 16 + 8]);
    *reinterpret_cast<float4*>(&bsv[12]) = *reinterpret_cast<const float4*>(&Bs[l * 16 + 12]);
#pragma unroll
    for (int s = 0; s < 16; ++s)
      h[s] = fmaf(__expf(dv * A[s]), h[s], du * bsv[s]);
    dv = dvn; uv = uvn;
  }
  float* hp = hend + (((size_t)n * NC + c) * 128 + d) * 16;
  *reinterpret_cast<float4*>(&hp[0])  = make_float4(h[0], h[1], h[2], h[3]);
  *reinterpret_cast<float4*>(&hp[4])  = make_float4(h[4], h[5], h[6], h[7]);
  *reinterpret_cast<float4*>(&hp[8])  = make_float4(h[8], h[9], h[10], h[11]);
  *reinterpret_cast<float4*>(&hp[12]) = make_float4(h[12], h[13], h[14], h[15]);
  Sdelta[((size_t)n * NC + c) * 128 + d] = sd;
}

// ---------------- K4b: cross-chunk combine (in-place hend -> Hstart prefix) ----------------
// thread = (n, d, s); 64 sequential chunk steps.
__global__ __launch_bounds__(256) void k4b_combine(
    const float* __restrict__ Sdelta, const float* __restrict__ A_log,
    float* __restrict__ hend) {
  int n = blockIdx.x >> 3, d0 = (blockIdx.x & 7) * 16;
  int d = d0 + (threadIdx.x >> 4), s = threadIdx.x & 15;
  float A = -__expf(A_log[d * 16 + s]);
  float H = 0.f;
  size_t i0 = ((size_t)n * NC) * 128 + d;
  float sd = Sdelta[i0];
  float he = hend[i0 * 16 + s];
  for (int c = 0; c < NC; ++c) {
    int cn = (c + 1 < NC) ? c + 1 : c;
    size_t in_ = ((size_t)n * NC + cn) * 128 + d;
    float sdn = Sdelta[in_];
    float hen = hend[in_ * 16 + s];
    size_t i = ((size_t)n * NC + c) * 128 + d;
    hend[i * 16 + s] = H;                    // store prefix (H before chunk c)
    H = fmaf(__expf(A * sd), H, he);
    sd = sdn; he = hen;
  }
}

// ---------------- K4c: per-chunk re-scan from Hstart, emit y ----------------
__global__ __launch_bounds__(128) void k4c_scan(
    const float* __restrict__ delta, const float* __restrict__ u,
    const float* __restrict__ Bc, const float* __restrict__ Cc,
    const float* __restrict__ A_log, const float* __restrict__ Hstart,
    float* __restrict__ y) {
  int c = blockIdx.x, n = blockIdx.y, d = threadIdx.x;
  __shared__ float Bs[CH * 16];
  __shared__ float Cs[CH * 16];
  const float* bsrc = Bc + ((size_t)n * L_ + c * CH) * 16;
  const float* csrc = Cc + ((size_t)n * L_ + c * CH) * 16;
  for (int e = d; e < CH * 16; e += 128) { Bs[e] = bsrc[e]; Cs[e] = csrc[e]; }
  float A[16];
#pragma unroll
  for (int s = 0; s < 16; ++s) A[s] = -__expf(A_log[d * 16 + s]);
  __syncthreads();

  const float* hp = Hstart + (((size_t)n * NC + c) * 128 + d) * 16;
  float h[16];
  *reinterpret_cast<float4*>(&h[0])  = *reinterpret_cast<const float4*>(&hp[0]);
  *reinterpret_cast<float4*>(&h[4])  = *reinterpret_cast<const float4*>(&hp[4]);
  *reinterpret_cast<float4*>(&h[8])  = *reinterpret_cast<const float4*>(&hp[8]);
  *reinterpret_cast<float4*>(&h[12]) = *reinterpret_cast<const float4*>(&hp[12]);

  const float* dp = delta + ((size_t)n * L_ + c * CH) * 128 + d;
  const float* up = u + ((size_t)n * L_ + c * CH) * 128 + d;
  float* yp = y + ((size_t)n * L_ + c * CH) * 128 + d;
  float dv = dp[0], uv = up[0];
  for (int l = 0; l < CH; ++l) {
    int ln = (l + 1 < CH) ? l + 1 : l;
    float dvn = dp[(size_t)ln * 128];
    float uvn = up[(size_t)ln * 128];
    float du = dv * uv;
    float bsv[16], csv[16];
    *reinterpret_cast<float4*>(&bsv[0])  = *reinterpret_cast<const float4*>(&Bs[l * 16 + 0]);
    *reinterpret_cast<float4*>(&bsv[4])  = *reinterpret_cast<const float4*>(&Bs[l * 16 + 4]);
    *reinterpret_cast<float4*>(&bsv[8])  = *reinterpret_cast<const float4*>(&Bs[l * 16 + 8]);
    *reinterpret_cast<float4*>(&bsv[12]) = *reinterpret_cast<const float4*>(&Bs[l * 16 + 12]);
    *reinterpret_cast<float4*>(&csv[0])  = *reinterpret_cast<const float4*>(&Cs[l * 16 + 0]);
    *reinterpret_cast<float4*>(&csv[4])  = *reinterpret_cast<const float4*>(&Cs[l * 16 + 4]);
    *reinterpret_cast<float4*>(&csv[8])  = *reinterpret_cast<const float4*>(&Cs[l * 16 + 8]);
    *reinterpret_cast<float4*>(&csv[12]) = *reinterpret_cast<const float4*>(&Cs[l * 16 + 12]);
    float yv = 0.f;
#pragma unroll
    for (int s = 0; s < 16; ++s) {
      h[s] = fmaf(__expf(dv * A[s]), h[s], du * bsv[s]);
      yv = fmaf(h[s], csv[s], yv);
    }
    yp[(size_t)l * 128] = yv;
    dv = dvn; uv = uvn;
  }
}

// ---------------- K5: gate + out_proj GEMM + skip ----------------
__global__ __launch_bounds__(256) void k5_gate_outproj(
    const float* __restrict__ y, const float* __restrict__ u,
    const float* __restrict__ z, const float* __restrict__ Dv,
    const float* __restrict__ ow, const float* __restrict__ stacked,
    const float* __restrict__ skip, float* __restrict__ ym) {
  int n = blockIdx.y, l0 = blockIdx.x * 64;
  __shared__ float As[64][132];
  __shared__ float Ws[64][132];
  int t = threadIdx.y * 16 + threadIdx.x;
  for (int e = t; e < 64 * 128; e += 256) {
    int r = e >> 7, c = e & 127;
    size_t idx = ((size_t)n * L_ + l0 + r) * 128 + c;
    float zz = z[idx];
    As[r][c] = (y[idx] + u[idx] * Dv[c]) * (zz / (1.f + __expf(-zz)));
    Ws[r][c] = ow[(size_t)r * 128 + c];
  }
  __syncthreads();
  float acc[4][4] = {};
  for (int jj = 0; jj < 32; ++jj) {
    float4 a[4], bm[4];
#pragma unroll
    for (int i = 0; i < 4; i++) a[i] = *reinterpret_cast<const float4*>(&As[threadIdx.y * 4 + i][jj * 4]);
#pragma unroll
    for (int i = 0; i < 4; i++) bm[i] = *reinterpret_cast<const float4*>(&Ws[threadIdx.x * 4 + i][jj * 4]);
#pragma unroll
    for (int i = 0; i < 4; i++)
#pragma unroll
      for (int kk = 0; kk < 4; kk++)
        acc[i][kk] += a[i].x * bm[kk].x + a[i].y * bm[kk].y + a[i].z * bm[kk].z + a[i].w * bm[kk].w;
  }
  float sk = skip[0];
#pragma unroll
  for (int i = 0; i < 4; i++) {
    int l = l0 + threadIdx.y * 4 + i;
    const float4 st = *reinterpret_cast<const float4*>(&stacked[((size_t)n * L_ + l) * 64 + threadIdx.x * 4]);
    float4 v = make_float4(acc[i][0] + sk * st.x, acc[i][1] + sk * st.y,
                           acc[i][2] + sk * st.z, acc[i][3] + sk * st.w);
    *reinterpret_cast<float4*>(&ym[((size_t)n * L_ + l) * 64 + threadIdx.x * 4]) = v;
  }
}

// ---------------- K6a: inverse shuffle + LayerNorm2 ----------------
__global__ __launch_bounds__(256) void k6a_ln2(
    const float* __restrict__ ym, const float* __restrict__ g,
    const float* __restrict__ bb, float* __restrict__ xmn) {
  int b = blockIdx.y;
  int l = blockIdx.x * 256 + threadIdx.x;
  float sum = 0.f, sq = 0.f;
  for (int c = 0; c < 256; ++c) {
    int gi = (c + 32) & 255;
    int br = gi >> 6, j = gi & 63;
    float v = ym[((size_t)(br * 4 + b) * L_ + l) * 64 + j];
    sum += v; sq += v * v;
  }
  float mean = sum * (1.0f / 256), rstd = rsqrtf(sq * (1.0f / 256) - mean * mean + 1e-5f);
  for (int c = 0; c < 256; ++c) {
    int gi = (c + 32) & 255;
    int br = gi >> 6, j = gi & 63;
    float v = ym[((size_t)(br * 4 + b) * L_ + l) * 64 + j];
    xmn[((size_t)b * L_ + l) * 256 + c] = (v - mean) * rstd * g[c] + bb[c];
  }
}

// ---------------- K6b: final 256x256 GEMM + bias + transpose store ----------------
__global__ __launch_bounds__(256) void k6b_proj(
    const float* __restrict__ xmn, const float* __restrict__ pw,
    const float* __restrict__ pb, float* __restrict__ out) {
  int b = blockIdx.z, k0 = blockIdx.y * 64, l0 = blockIdx.x * 64;
  __shared__ float As[64][68];
  __shared__ float Ws[64][68];
  int t = threadIdx.y * 16 + threadIdx.x;
  float acc[4][4] = {};
  for (int cc = 0; cc < 4; ++cc) {
    __syncthreads();
    for (int e = t; e < 4096; e += 256) {
      int r = e >> 6, c = e & 63;
      As[r][c] = xmn[((size_t)b * L_ + l0 + r) * 256 + cc * 64 + c];
      Ws[r][c] = pw[(k0 + r) * 256 + cc * 64 + c];
    }
    __syncthreads();
    for (int jj = 0; jj < 16; ++jj) {
      float4 a[4], bm[4];
#pragma unroll
      for (int i = 0; i < 4; i++) a[i] = *reinterpret_cast<const float4*>(&As[threadIdx.y * 4 + i][jj * 4]);
#pragma unroll
      for (int i = 0; i < 4; i++) bm[i] = *reinterpret_cast<const float4*>(&Ws[threadIdx.x * 4 + i][jj * 4]);
#pragma unroll
      for (int i = 0; i < 4; i++)
#pragma unroll
        for (int kk = 0; kk < 4; kk++)
          acc[i][kk] += a[i].x * bm[kk].x + a[i].y * bm[kk].y + a[i].z * bm[kk].z + a[i].w * bm[kk].w;
    }
  }
#pragma unroll
  for (int kk = 0; kk < 4; kk++) {
    int k = k0 + threadIdx.x * 4 + kk;
    float pbv = pb[k];
#pragma unroll
    for (int i = 0; i < 4; i++) {
      int l = l0 + threadIdx.y * 4 + i;
      out[((size_t)b * 256 + k) * L_ + l] = acc[i][kk] + pbv;
    }
  }
}

extern "C" void kernel_launch(void* const* d_in, const int* in_sizes, int n_in,
                              void* d_out, int out_size, void* d_ws, size_t ws_size,
                              hipStream_t stream) {
  const float* x        = (const float*)d_in[0];
  const float* norm_g   = (const float*)d_in[1];
  const float* norm_b   = (const float*)d_in[2];
  const float* skip     = (const float*)d_in[3];
  const float* proj_w   = (const float*)d_in[4];
  const float* proj_b   = (const float*)d_in[5];
  const float* in_proj_w= (const float*)d_in[6];
  const float* conv_w   = (const float*)d_in[7];
  const float* conv_b   = (const float*)d_in[8];
  const float* x_proj_w = (const float*)d_in[9];
  const float* dt_w     = (const float*)d_in[10];
  const float* dt_b     = (const float*)d_in[11];
  const float* A_log    = (const float*)d_in[12];
  const float* Dv       = (const float*)d_in[13];
  const float* out_w    = (const float*)d_in[14];
  float* out = (float*)d_out;
  float* ws  = (float*)d_ws;

  // workspace layout (floats)
  float* stacked = ws;                    // 16*4096*64   = 4,194,304
  float* xi      = ws + 4194304;          // 16*4096*128  = 8,388,608  (reused as y after K4)
  float* z       = ws + 12582912;         // 8,388,608
  float* u       = ws + 20971520;         // 8,388,608
  float* delta   = ws + 29360128;         // 8,388,608   (reused: ym + xmn after K4)
  float* Bc      = ws + 37748736;         // 1,048,576
  float* Cc      = ws + 38797312;         // 1,048,576
  float* ym      = delta;                 // 4,194,304
  float* xmn     = delta + 4194304;       // 4,194,304

  // scan scratch lives in d_out (4M floats; fully overwritten by k6b at the end)
  float* hend   = out;                    // 16*64*128*16 = 2,097,152 (becomes Hstart in k4b)
  float* Sdelta = out + 2097152;          // 16*64*128    =   131,072

  k1_ln_scatter<<<dim3(16, 4), 256, 0, stream>>>(x, norm_g, norm_b, stacked);
  k2_inproj<<<dim3(64, 4, 16), dim3(16, 16), 0, stream>>>(stacked, in_proj_w, xi, z);
  k3_conv_xproj<<<dim3(32, 16), 128, 0, stream>>>(xi, conv_w, conv_b, x_proj_w,
                                                  dt_w, dt_b, u, delta, Bc, Cc);
  k4a_chunk<<<dim3(NC, 16), 128, 0, stream>>>(delta, u, Bc, A_log, hend, Sdelta);
  k4b_combine<<<128, 256, 0, stream>>>(Sdelta, A_log, hend);
  k4c_scan<<<dim3(NC, 16), 128, 0, stream>>>(delta, u, Bc, Cc, A_log, hend, xi /*y*/);
  k5_gate_outproj<<<dim3(64, 16), dim3(16, 16), 0, stream>>>(xi /*y*/, u, z, Dv,
                                                             out_w, stacked, skip, ym);
  k6a_ln2<<<dim3(16, 4), 256, 0, stream>>>(ym, norm_g, norm_b, xmn);
  k6b_proj<<<dim3(64, 4, 4), dim3(16, 16), 0, stream>>>(xmn, proj_w, proj_b, out);
}

// Round 4
// 434.070 us; speedup vs baseline: 3.5652x; 1.3178x over previous
//
#include <hip/hip_runtime.h>
#include <hip/hip_bf16.h>

#define L_ 4096
#define CCH 256
#define CH 64     // scan chunk length
#define NC 64     // number of chunks (L_/CH)

// ---------------- K1: LayerNorm over C + branch scatter (LDS transpose) ----------------
// x: [4][256][4096] -> stacked: [16][4096][64]; stacked[br*4+b][l][j] = xn[b][l][(br*64+j+224)&255]
__global__ __launch_bounds__(256) void k1_ln_scatter(
    const float* __restrict__ x, const float* __restrict__ g,
    const float* __restrict__ bb, float* __restrict__ stacked) {
  int b = blockIdx.y;
  int l0 = blockIdx.x * 64;
  int t = threadIdx.x;
  int lane = t & 63, w = t >> 6;
  __shared__ float xs[256][65];
  __shared__ float ps[4][64], ps2[4][64];
  __shared__ float mean_s[64], rstd_s[64];
  // stage: wave w loads rows c = w + 4i, lanes along l (coalesced 256B)
  for (int i = 0; i < 64; ++i) {
    int c = w + 4 * i;
    xs[c][lane] = x[((size_t)b * 256 + c) * L_ + l0 + lane];
  }
  __syncthreads();
  // partial reduce: thread (l=lane, cg=w) sums 64 channels
  float sum = 0.f, sq = 0.f;
  for (int c = w * 64; c < w * 64 + 64; ++c) {
    float v = xs[c][lane];
    sum += v; sq += v * v;
  }
  ps[w][lane] = sum; ps2[w][lane] = sq;
  __syncthreads();
  if (w == 0) {
    float s = ps[0][lane] + ps[1][lane] + ps[2][lane] + ps[3][lane];
    float q = ps2[0][lane] + ps2[1][lane] + ps2[2][lane] + ps2[3][lane];
    float mean = s * (1.f / 256.f);
    mean_s[lane] = mean;
    rstd_s[lane] = rsqrtf(q * (1.f / 256.f) - mean * mean + 1e-5f);
  }
  __syncthreads();
  // write: wave w = branch br, lane = j; c fixed per thread
  int br = w, j = lane;
  int c = (br * 64 + j + 224) & 255;
  float gv = g[c], bv = bb[c];
  float* dst = stacked + ((size_t)(br * 4 + b) * L_ + l0) * 64 + j;
  for (int l = 0; l < 64; ++l) {
    float v = (xs[c][l] - mean_s[l]) * rstd_s[l] * gv + bv;
    dst[(size_t)l * 64] = v;
  }
}

// ---------------- K2: in_proj GEMM  xz = stacked @ W^T ----------------
__global__ __launch_bounds__(256) void k2_inproj(
    const float* __restrict__ stacked, const float* __restrict__ w,
    float* __restrict__ xi, float* __restrict__ z) {
  int n = blockIdx.z, l0 = blockIdx.x * 64, k0 = blockIdx.y * 64;
  __shared__ float As[64][68];
  __shared__ float Ws[64][68];
  int t = threadIdx.y * 16 + threadIdx.x;
  for (int e = t; e < 4096; e += 256) {
    int r = e >> 6, c = e & 63;
    As[r][c] = stacked[((size_t)n * L_ + l0 + r) * 64 + c];
    Ws[r][c] = w[(k0 + r) * 64 + c];
  }
  __syncthreads();
  float acc[4][4] = {};
  for (int jj = 0; jj < 16; ++jj) {
    float4 a[4], bm[4];
#pragma unroll
    for (int i = 0; i < 4; i++) a[i] = *reinterpret_cast<const float4*>(&As[threadIdx.y * 4 + i][jj * 4]);
#pragma unroll
    for (int i = 0; i < 4; i++) bm[i] = *reinterpret_cast<const float4*>(&Ws[threadIdx.x * 4 + i][jj * 4]);
#pragma unroll
    for (int i = 0; i < 4; i++)
#pragma unroll
      for (int kk = 0; kk < 4; kk++)
        acc[i][kk] += a[i].x * bm[kk].x + a[i].y * bm[kk].y + a[i].z * bm[kk].z + a[i].w * bm[kk].w;
  }
  int kb = k0 + threadIdx.x * 4;
  float* dst = (kb < 128) ? xi : z;
  int kd = (kb < 128) ? kb : kb - 128;
#pragma unroll
  for (int i = 0; i < 4; i++) {
    int l = l0 + threadIdx.y * 4 + i;
    float4 v = make_float4(acc[i][0], acc[i][1], acc[i][2], acc[i][3]);
    *reinterpret_cast<float4*>(&dst[((size_t)n * L_ + l) * 128 + kd]) = v;
  }
}

// ---------------- K3: fused causal conv1d + silu + x_proj + dt_proj + softplus ----------------
// block = 64 threads (thread = l), grid (L/64, 16). LDS: 67-row halo tile only.
__global__ __launch_bounds__(64) void k3_conv_xproj(
    const float* __restrict__ xi, const float* __restrict__ cw,
    const float* __restrict__ cb, const float* __restrict__ xw,
    const float* __restrict__ dtw, const float* __restrict__ dtb,
    float* __restrict__ u, float* __restrict__ delta,
    float* __restrict__ Bc, float* __restrict__ Cc) {
  int n = blockIdx.y, l0 = blockIdx.x * 64, t = threadIdx.x;
  __shared__ float xt[67][129];   // rows l0-3 .. l0+63, padded stride 129
  __shared__ float dtl[64][4];
  // stage xi halo tile, float4 coalesced
  for (int e4 = t; e4 < 67 * 32; e4 += 64) {
    int r = e4 >> 5, c = (e4 & 31) * 4;
    int gl = l0 - 3 + r;
    float4 v = make_float4(0.f, 0.f, 0.f, 0.f);
    if (gl >= 0) v = *reinterpret_cast<const float4*>(&xi[((size_t)n * L_ + gl) * 128 + c]);
    *reinterpret_cast<float4*>(&xt[r][c]) = v;
  }
  __syncthreads();
  int l = t;
  size_t rowbase = ((size_t)n * L_ + l0 + l) * 128;
  float acc36[36] = {};
  for (int d = 0; d < 128; ++d) {
    float c0 = cw[d * 4 + 0], c1 = cw[d * 4 + 1], c2 = cw[d * 4 + 2], c3 = cw[d * 4 + 3];
    float s = cb[d] + xt[l][d] * c0 + xt[l + 1][d] * c1 + xt[l + 2][d] * c2 + xt[l + 3][d] * c3;
    float uv = s / (1.f + __expf(-s));  // silu
    u[rowbase + d] = uv;
#pragma unroll
    for (int r = 0; r < 36; ++r) acc36[r] += uv * xw[r * 128 + d];
  }
  // B/C writes: 16 consecutive floats each per thread
  {
    size_t base = ((size_t)n * L_ + l0 + l) * 16;
    float4* bp = reinterpret_cast<float4*>(Bc + base);
    bp[0] = make_float4(acc36[4], acc36[5], acc36[6], acc36[7]);
    bp[1] = make_float4(acc36[8], acc36[9], acc36[10], acc36[11]);
    bp[2] = make_float4(acc36[12], acc36[13], acc36[14], acc36[15]);
    bp[3] = make_float4(acc36[16], acc36[17], acc36[18], acc36[19]);
    float4* cp = reinterpret_cast<float4*>(Cc + base);
    cp[0] = make_float4(acc36[20], acc36[21], acc36[22], acc36[23]);
    cp[1] = make_float4(acc36[24], acc36[25], acc36[26], acc36[27]);
    cp[2] = make_float4(acc36[28], acc36[29], acc36[30], acc36[31]);
    cp[3] = make_float4(acc36[32], acc36[33], acc36[34], acc36[35]);
  }
  dtl[l][0] = acc36[0]; dtl[l][1] = acc36[1]; dtl[l][2] = acc36[2]; dtl[l][3] = acc36[3];
  __syncthreads();
  // delta: lanes along d (two halves), coalesced 256B stores
  float4 w0 = *reinterpret_cast<const float4*>(&dtw[t * 4]);
  float4 w1 = *reinterpret_cast<const float4*>(&dtw[(t + 64) * 4]);
  float b0 = dtb[t], b1 = dtb[t + 64];
  for (int l2 = 0; l2 < 64; ++l2) {
    float q0 = dtl[l2][0], q1 = dtl[l2][1], q2 = dtl[l2][2], q3 = dtl[l2][3];
    float dv0 = b0 + q0 * w0.x + q1 * w0.y + q2 * w0.z + q3 * w0.w;
    float dv1 = b1 + q0 * w1.x + q1 * w1.y + q2 * w1.z + q3 * w1.w;
    dv0 = (dv0 > 20.f) ? dv0 : log1pf(__expf(dv0));
    dv1 = (dv1 > 20.f) ? dv1 : log1pf(__expf(dv1));
    size_t base = ((size_t)n * L_ + l0 + l2) * 128;
    delta[base + t] = dv0;
    delta[base + t + 64] = dv1;
  }
}

// ---------------- K4a: per-chunk local scan (h from 0) + chunk delta-sum ----------------
__global__ __launch_bounds__(128) void k4a_chunk(
    const float* __restrict__ delta, const float* __restrict__ u,
    const float* __restrict__ Bc, const float* __restrict__ A_log,
    float* __restrict__ hend, float* __restrict__ Sdelta) {
  int c = blockIdx.x, n = blockIdx.y, d = threadIdx.x;
  __shared__ float Bs[CH * 16];
  const float* bsrc = Bc + ((size_t)n * L_ + c * CH) * 16;
  for (int e = d; e < CH * 16; e += 128) Bs[e] = bsrc[e];
  float A[16];
#pragma unroll
  for (int s = 0; s < 16; ++s) A[s] = -__expf(A_log[d * 16 + s]);
  __syncthreads();

  const float* dp = delta + ((size_t)n * L_ + c * CH) * 128 + d;
  const float* up = u + ((size_t)n * L_ + c * CH) * 128 + d;
  float h[16] = {};
  float sd = 0.f;
  float dv = dp[0], uv = up[0];
  for (int l = 0; l < CH; ++l) {
    int ln = (l + 1 < CH) ? l + 1 : l;
    float dvn = dp[(size_t)ln * 128];
    float uvn = up[(size_t)ln * 128];
    sd += dv;
    float du = dv * uv;
    float bsv[16];
    *reinterpret_cast<float4*>(&bsv[0])  = *reinterpret_cast<const float4*>(&Bs[l * 16 + 0]);
    *reinterpret_cast<float4*>(&bsv[4])  = *reinterpret_cast<const float4*>(&Bs[l * 16 + 4]);
    *reinterpret_cast<float4*>(&bsv[8])  = *reinterpret_cast<const float4*>(&Bs[l * 16 + 8]);
    *reinterpret_cast<float4*>(&bsv[12]) = *reinterpret_cast<const float4*>(&Bs[l * 16 + 12]);
#pragma unroll
    for (int s = 0; s < 16; ++s)
      h[s] = fmaf(__expf(dv * A[s]), h[s], du * bsv[s]);
    dv = dvn; uv = uvn;
  }
  float* hp = hend + (((size_t)n * NC + c) * 128 + d) * 16;
  *reinterpret_cast<float4*>(&hp[0])  = make_float4(h[0], h[1], h[2], h[3]);
  *reinterpret_cast<float4*>(&hp[4])  = make_float4(h[4], h[5], h[6], h[7]);
  *reinterpret_cast<float4*>(&hp[8])  = make_float4(h[8], h[9], h[10], h[11]);
  *reinterpret_cast<float4*>(&hp[12]) = make_float4(h[12], h[13], h[14], h[15]);
  Sdelta[((size_t)n * NC + c) * 128 + d] = sd;
}

// ---------------- K4b: cross-chunk combine (in-place hend -> Hstart prefix) ----------------
__global__ __launch_bounds__(256) void k4b_combine(
    const float* __restrict__ Sdelta, const float* __restrict__ A_log,
    float* __restrict__ hend) {
  int n = blockIdx.x >> 3, d0 = (blockIdx.x & 7) * 16;
  int d = d0 + (threadIdx.x >> 4), s = threadIdx.x & 15;
  float A = -__expf(A_log[d * 16 + s]);
  float H = 0.f;
  size_t i0 = ((size_t)n * NC) * 128 + d;
  float sd = Sdelta[i0];
  float he = hend[i0 * 16 + s];
  for (int c = 0; c < NC; ++c) {
    int cn = (c + 1 < NC) ? c + 1 : c;
    size_t in_ = ((size_t)n * NC + cn) * 128 + d;
    float sdn = Sdelta[in_];
    float hen = hend[in_ * 16 + s];
    size_t i = ((size_t)n * NC + c) * 128 + d;
    hend[i * 16 + s] = H;                    // store prefix (H before chunk c)
    H = fmaf(__expf(A * sd), H, he);
    sd = sdn; he = hen;
  }
}

// ---------------- K4c: per-chunk re-scan from Hstart, emit y ----------------
__global__ __launch_bounds__(128) void k4c_scan(
    const float* __restrict__ delta, const float* __restrict__ u,
    const float* __restrict__ Bc, const float* __restrict__ Cc,
    const float* __restrict__ A_log, const float* __restrict__ Hstart,
    float* __restrict__ y) {
  int c = blockIdx.x, n = blockIdx.y, d = threadIdx.x;
  __shared__ float Bs[CH * 16];
  __shared__ float Cs[CH * 16];
  const float* bsrc = Bc + ((size_t)n * L_ + c * CH) * 16;
  const float* csrc = Cc + ((size_t)n * L_ + c * CH) * 16;
  for (int e = d; e < CH * 16; e += 128) { Bs[e] = bsrc[e]; Cs[e] = csrc[e]; }
  float A[16];
#pragma unroll
  for (int s = 0; s < 16; ++s) A[s] = -__expf(A_log[d * 16 + s]);
  __syncthreads();

  const float* hp = Hstart + (((size_t)n * NC + c) * 128 + d) * 16;
  float h[16];
  *reinterpret_cast<float4*>(&h[0])  = *reinterpret_cast<const float4*>(&hp[0]);
  *reinterpret_cast<float4*>(&h[4])  = *reinterpret_cast<const float4*>(&hp[4]);
  *reinterpret_cast<float4*>(&h[8])  = *reinterpret_cast<const float4*>(&hp[8]);
  *reinterpret_cast<float4*>(&h[12]) = *reinterpret_cast<const float4*>(&hp[12]);

  const float* dp = delta + ((size_t)n * L_ + c * CH) * 128 + d;
  const float* up = u + ((size_t)n * L_ + c * CH) * 128 + d;
  float* yp = y + ((size_t)n * L_ + c * CH) * 128 + d;
  float dv = dp[0], uv = up[0];
  for (int l = 0; l < CH; ++l) {
    int ln = (l + 1 < CH) ? l + 1 : l;
    float dvn = dp[(size_t)ln * 128];
    float uvn = up[(size_t)ln * 128];
    float du = dv * uv;
    float bsv[16], csv[16];
    *reinterpret_cast<float4*>(&bsv[0])  = *reinterpret_cast<const float4*>(&Bs[l * 16 + 0]);
    *reinterpret_cast<float4*>(&bsv[4])  = *reinterpret_cast<const float4*>(&Bs[l * 16 + 4]);
    *reinterpret_cast<float4*>(&bsv[8])  = *reinterpret_cast<const float4*>(&Bs[l * 16 + 8]);
    *reinterpret_cast<float4*>(&bsv[12]) = *reinterpret_cast<const float4*>(&Bs[l * 16 + 12]);
    *reinterpret_cast<float4*>(&csv[0])  = *reinterpret_cast<const float4*>(&Cs[l * 16 + 0]);
    *reinterpret_cast<float4*>(&csv[4])  = *reinterpret_cast<const float4*>(&Cs[l * 16 + 4]);
    *reinterpret_cast<float4*>(&csv[8])  = *reinterpret_cast<const float4*>(&Cs[l * 16 + 8]);
    *reinterpret_cast<float4*>(&csv[12]) = *reinterpret_cast<const float4*>(&Cs[l * 16 + 12]);
    float yv = 0.f;
#pragma unroll
    for (int s = 0; s < 16; ++s) {
      h[s] = fmaf(__expf(dv * A[s]), h[s], du * bsv[s]);
      yv = fmaf(h[s], csv[s], yv);
    }
    yp[(size_t)l * 128] = yv;
    dv = dvn; uv = uvn;
  }
}

// ---------------- K5: gate + out_proj GEMM + skip ----------------
__global__ __launch_bounds__(256) void k5_gate_outproj(
    const float* __restrict__ y, const float* __restrict__ u,
    const float* __restrict__ z, const float* __restrict__ Dv,
    const float* __restrict__ ow, const float* __restrict__ stacked,
    const float* __restrict__ skip, float* __restrict__ ym) {
  int n = blockIdx.y, l0 = blockIdx.x * 64;
  __shared__ float As[64][132];
  __shared__ float Ws[64][132];
  int t = threadIdx.y * 16 + threadIdx.x;
  for (int e = t; e < 64 * 128; e += 256) {
    int r = e >> 7, c = e & 127;
    size_t idx = ((size_t)n * L_ + l0 + r) * 128 + c;
    float zz = z[idx];
    As[r][c] = (y[idx] + u[idx] * Dv[c]) * (zz / (1.f + __expf(-zz)));
    Ws[r][c] = ow[(size_t)r * 128 + c];
  }
  __syncthreads();
  float acc[4][4] = {};
  for (int jj = 0; jj < 32; ++jj) {
    float4 a[4], bm[4];
#pragma unroll
    for (int i = 0; i < 4; i++) a[i] = *reinterpret_cast<const float4*>(&As[threadIdx.y * 4 + i][jj * 4]);
#pragma unroll
    for (int i = 0; i < 4; i++) bm[i] = *reinterpret_cast<const float4*>(&Ws[threadIdx.x * 4 + i][jj * 4]);
#pragma unroll
    for (int i = 0; i < 4; i++)
#pragma unroll
      for (int kk = 0; kk < 4; kk++)
        acc[i][kk] += a[i].x * bm[kk].x + a[i].y * bm[kk].y + a[i].z * bm[kk].z + a[i].w * bm[kk].w;
  }
  float sk = skip[0];
#pragma unroll
  for (int i = 0; i < 4; i++) {
    int l = l0 + threadIdx.y * 4 + i;
    const float4 st = *reinterpret_cast<const float4*>(&stacked[((size_t)n * L_ + l) * 64 + threadIdx.x * 4]);
    float4 v = make_float4(acc[i][0] + sk * st.x, acc[i][1] + sk * st.y,
                           acc[i][2] + sk * st.z, acc[i][3] + sk * st.w);
    *reinterpret_cast<float4*>(&ym[((size_t)n * L_ + l) * 64 + threadIdx.x * 4]) = v;
  }
}

// ---------------- K6a: inverse shuffle + LayerNorm2 (wave per (b,l)) ----------------
__global__ __launch_bounds__(256) void k6a_ln2(
    const float* __restrict__ ym, const float* __restrict__ g,
    const float* __restrict__ bb, float* __restrict__ xmn) {
  int b = blockIdx.y;
  int l = blockIdx.x * 4 + (threadIdx.x >> 6);
  int j = threadIdx.x & 63;
  float v[4];
  float sum = 0.f, sq = 0.f;
#pragma unroll
  for (int br = 0; br < 4; ++br) {
    v[br] = ym[((size_t)(br * 4 + b) * L_ + l) * 64 + j];
    sum += v[br]; sq += v[br] * v[br];
  }
#pragma unroll
  for (int off = 1; off < 64; off <<= 1) {
    sum += __shfl_xor(sum, off);
    sq  += __shfl_xor(sq, off);
  }
  float mean = sum * (1.f / 256.f);
  float rstd = rsqrtf(sq * (1.f / 256.f) - mean * mean + 1e-5f);
#pragma unroll
  for (int br = 0; br < 4; ++br) {
    int c = (br * 64 + j + 224) & 255;
    xmn[((size_t)b * L_ + l) * 256 + c] = (v[br] - mean) * rstd * g[c] + bb[c];
  }
}

// ---------------- K6b: final 256x256 GEMM + bias, LDS-transposed coalesced store ----------------
__global__ __launch_bounds__(256) void k6b_proj(
    const float* __restrict__ xmn, const float* __restrict__ pw,
    const float* __restrict__ pb, float* __restrict__ out) {
  int b = blockIdx.z, k0 = blockIdx.y * 64, l0 = blockIdx.x * 64;
  __shared__ float As[64][68];
  __shared__ float Ws[64][68];
  int t = threadIdx.y * 16 + threadIdx.x;
  float acc[4][4] = {};
  for (int cc = 0; cc < 4; ++cc) {
    __syncthreads();
    for (int e = t; e < 4096; e += 256) {
      int r = e >> 6, c = e & 63;
      As[r][c] = xmn[((size_t)b * L_ + l0 + r) * 256 + cc * 64 + c];
      Ws[r][c] = pw[(k0 + r) * 256 + cc * 64 + c];
    }
    __syncthreads();
    for (int jj = 0; jj < 16; ++jj) {
      float4 a[4], bm[4];
#pragma unroll
      for (int i = 0; i < 4; i++) a[i] = *reinterpret_cast<const float4*>(&As[threadIdx.y * 4 + i][jj * 4]);
#pragma unroll
      for (int i = 0; i < 4; i++) bm[i] = *reinterpret_cast<const float4*>(&Ws[threadIdx.x * 4 + i][jj * 4]);
#pragma unroll
      for (int i = 0; i < 4; i++)
#pragma unroll
        for (int kk = 0; kk < 4; kk++)
          acc[i][kk] += a[i].x * bm[kk].x + a[i].y * bm[kk].y + a[i].z * bm[kk].z + a[i].w * bm[kk].w;
    }
  }
  // stage C tile to LDS (stride 65: conflict-free read side), then coalesced store
  __syncthreads();
  float* Ct = &As[0][0];
#pragma unroll
  for (int i = 0; i < 4; i++)
#pragma unroll
    for (int kk = 0; kk < 4; kk++)
      Ct[(threadIdx.y * 4 + i) * 65 + (threadIdx.x * 4 + kk)] = acc[i][kk];
  __syncthreads();
  int lane64 = t & 63, w = t >> 6;
#pragma unroll
  for (int p = 0; p < 16; ++p) {
    int row = p * 4 + w;
    out[((size_t)b * 256 + k0 + row) * L_ + l0 + lane64] = Ct[lane64 * 65 + row] + pb[k0 + row];
  }
}

extern "C" void kernel_launch(void* const* d_in, const int* in_sizes, int n_in,
                              void* d_out, int out_size, void* d_ws, size_t ws_size,
                              hipStream_t stream) {
  const float* x        = (const float*)d_in[0];
  const float* norm_g   = (const float*)d_in[1];
  const float* norm_b   = (const float*)d_in[2];
  const float* skip     = (const float*)d_in[3];
  const float* proj_w   = (const float*)d_in[4];
  const float* proj_b   = (const float*)d_in[5];
  const float* in_proj_w= (const float*)d_in[6];
  const float* conv_w   = (const float*)d_in[7];
  const float* conv_b   = (const float*)d_in[8];
  const float* x_proj_w = (const float*)d_in[9];
  const float* dt_w     = (const float*)d_in[10];
  const float* dt_b     = (const float*)d_in[11];
  const float* A_log    = (const float*)d_in[12];
  const float* Dv       = (const float*)d_in[13];
  const float* out_w    = (const float*)d_in[14];
  float* out = (float*)d_out;
  float* ws  = (float*)d_ws;

  // workspace layout (floats)
  float* stacked = ws;                    // 16*4096*64   = 4,194,304
  float* xi      = ws + 4194304;          // 16*4096*128  = 8,388,608  (reused as y after K4)
  float* z       = ws + 12582912;         // 8,388,608
  float* u       = ws + 20971520;         // 8,388,608
  float* delta   = ws + 29360128;         // 8,388,608   (reused: ym + xmn after K4)
  float* Bc      = ws + 37748736;         // 1,048,576
  float* Cc      = ws + 38797312;         // 1,048,576
  float* ym      = delta;                 // 4,194,304
  float* xmn     = delta + 4194304;       // 4,194,304

  // scan scratch lives in d_out (4M floats; fully overwritten by k6b at the end)
  float* hend   = out;                    // 16*64*128*16 = 2,097,152 (becomes Hstart in k4b)
  float* Sdelta = out + 2097152;          // 16*64*128    =   131,072

  k1_ln_scatter<<<dim3(64, 4), 256, 0, stream>>>(x, norm_g, norm_b, stacked);
  k2_inproj<<<dim3(64, 4, 16), dim3(16, 16), 0, stream>>>(stacked, in_proj_w, xi, z);
  k3_conv_xproj<<<dim3(64, 16), 64, 0, stream>>>(xi, conv_w, conv_b, x_proj_w,
                                                 dt_w, dt_b, u, delta, Bc, Cc);
  k4a_chunk<<<dim3(NC, 16), 128, 0, stream>>>(delta, u, Bc, A_log, hend, Sdelta);
  k4b_combine<<<128, 256, 0, stream>>>(Sdelta, A_log, hend);
  k4c_scan<<<dim3(NC, 16), 128, 0, stream>>>(delta, u, Bc, Cc, A_log, hend, xi /*y*/);
  k5_gate_outproj<<<dim3(64, 16), dim3(16, 16), 0, stream>>>(xi /*y*/, u, z, Dv,
                                                             out_w, stacked, skip, ym);
  k6a_ln2<<<dim3(1024, 4), 256, 0, stream>>>(ym, norm_g, norm_b, xmn);
  k6b_proj<<<dim3(64, 4, 4), dim3(16, 16), 0, stream>>>(xmn, proj_w, proj_b, out);
}

// Round 7
// 403.522 us; speedup vs baseline: 3.8351x; 1.0757x over previous
//
#include <hip/hip_runtime.h>
#include <hip/hip_bf16.h>

#define L_ 4096
#define CCH 256
#define CH 64     // scan chunk length
#define NC 64     // number of chunks (L_/CH)

// ---------------- K1: LayerNorm over C + branch scatter (LDS transpose) ----------------
// x: [4][256][4096] -> stacked: [16][4096][64]; stacked[br*4+b][l][j] = xn[b][l][(br*64+j+224)&255]
__global__ __launch_bounds__(256) void k1_ln_scatter(
    const float* __restrict__ x, const float* __restrict__ g,
    const float* __restrict__ bb, float* __restrict__ stacked) {
  int b = blockIdx.y;
  int l0 = blockIdx.x * 64;
  int t = threadIdx.x;
  int lane = t & 63, w = t >> 6;
  __shared__ float xs[256][65];
  __shared__ float ps[4][64], ps2[4][64];
  __shared__ float mean_s[64], rstd_s[64];
  for (int i = 0; i < 64; ++i) {
    int c = w + 4 * i;
    xs[c][lane] = x[((size_t)b * 256 + c) * L_ + l0 + lane];
  }
  __syncthreads();
  float sum = 0.f, sq = 0.f;
  for (int c = w * 64; c < w * 64 + 64; ++c) {
    float v = xs[c][lane];
    sum += v; sq += v * v;
  }
  ps[w][lane] = sum; ps2[w][lane] = sq;
  __syncthreads();
  if (w == 0) {
    float s = ps[0][lane] + ps[1][lane] + ps[2][lane] + ps[3][lane];
    float q = ps2[0][lane] + ps2[1][lane] + ps2[2][lane] + ps2[3][lane];
    float mean = s * (1.f / 256.f);
    mean_s[lane] = mean;
    rstd_s[lane] = rsqrtf(q * (1.f / 256.f) - mean * mean + 1e-5f);
  }
  __syncthreads();
  int br = w, j = lane;
  int c = (br * 64 + j + 224) & 255;
  float gv = g[c], bv = bb[c];
  float* dst = stacked + ((size_t)(br * 4 + b) * L_ + l0) * 64 + j;
  for (int l = 0; l < 64; ++l) {
    float v = (xs[c][l] - mean_s[l]) * rstd_s[l] * gv + bv;
    dst[(size_t)l * 64] = v;
  }
}

// ---------------- K2: in_proj GEMM  xz = stacked @ W^T ----------------
__global__ __launch_bounds__(256) void k2_inproj(
    const float* __restrict__ stacked, const float* __restrict__ w,
    float* __restrict__ xi, float* __restrict__ z) {
  int n = blockIdx.z, l0 = blockIdx.x * 64, k0 = blockIdx.y * 64;
  __shared__ float As[64][68];
  __shared__ float Ws[64][68];
  int t = threadIdx.y * 16 + threadIdx.x;
  for (int e = t; e < 4096; e += 256) {
    int r = e >> 6, c = e & 63;
    As[r][c] = stacked[((size_t)n * L_ + l0 + r) * 64 + c];
    Ws[r][c] = w[(k0 + r) * 64 + c];
  }
  __syncthreads();
  float acc[4][4] = {};
  for (int jj = 0; jj < 16; ++jj) {
    float4 a[4], bm[4];
#pragma unroll
    for (int i = 0; i < 4; i++) a[i] = *reinterpret_cast<const float4*>(&As[threadIdx.y * 4 + i][jj * 4]);
#pragma unroll
    for (int i = 0; i < 4; i++) bm[i] = *reinterpret_cast<const float4*>(&Ws[threadIdx.x * 4 + i][jj * 4]);
#pragma unroll
    for (int i = 0; i < 4; i++)
#pragma unroll
      for (int kk = 0; kk < 4; kk++)
        acc[i][kk] += a[i].x * bm[kk].x + a[i].y * bm[kk].y + a[i].z * bm[kk].z + a[i].w * bm[kk].w;
  }
  int kb = k0 + threadIdx.x * 4;
  float* dst = (kb < 128) ? xi : z;
  int kd = (kb < 128) ? kb : kb - 128;
#pragma unroll
  for (int i = 0; i < 4; i++) {
    int l = l0 + threadIdx.y * 4 + i;
    float4 v = make_float4(acc[i][0], acc[i][1], acc[i][2], acc[i][3]);
    *reinterpret_cast<float4*>(&dst[((size_t)n * L_ + l) * 128 + kd]) = v;
  }
}

// ---------------- K3: fused causal conv1d + silu + x_proj + dt_proj + softplus ----------------
// 256 threads, 64 l's per block. Phase A: lanes along d, register-carried conv history.
// Phase B: (l, q) 36-dot from LDS. Phase C: delta coalesced. Phase D: B/C via LDS.
__global__ __launch_bounds__(256) void k3_conv_xproj(
    const float* __restrict__ xi, const float* __restrict__ cw,
    const float* __restrict__ cb, const float* __restrict__ xw,
    const float* __restrict__ dtw, const float* __restrict__ dtb,
    float* __restrict__ u, float* __restrict__ delta,
    float* __restrict__ Bc, float* __restrict__ Cc) {
  int n = blockIdx.y, l0 = blockIdx.x * 64;
  int tid = threadIdx.x;
  __shared__ float us[64][129];
  __shared__ float dbls[64][37];

  // ---- Phase A: conv + silu, streaming over l with lanes along d ----
  {
    int d = tid & 127, lh = tid >> 7;      // lh in {0,1}
    int ls = l0 + lh * 32;                 // this thread streams l = ls .. ls+31
    const float* xp = xi + ((size_t)n * L_ + ls) * 128 + d;
    const float4 cwv = *reinterpret_cast<const float4*>(&cw[d * 4]);
    float cbv = cb[d];
    float xm3 = (ls >= 3) ? xp[-3 * 128] : 0.f;
    float xm2 = (ls >= 2) ? xp[-2 * 128] : 0.f;
    float xm1 = (ls >= 1) ? xp[-1 * 128] : 0.f;
    float* up = u + ((size_t)n * L_ + ls) * 128 + d;
#pragma unroll 4
    for (int l = 0; l < 32; ++l) {
      float xv = xp[(size_t)l * 128];
      float s = cbv + cwv.x * xm3 + cwv.y * xm2 + cwv.z * xm1 + cwv.w * xv;
      float uv = s / (1.f + __expf(-s));   // silu
      us[lh * 32 + l][d] = uv;
      up[(size_t)l * 128] = uv;
      xm3 = xm2; xm2 = xm1; xm1 = xv;
    }
  }
  __syncthreads();

  // ---- Phase B: dbl[l][r] = sum_d u[l][d] * xw[r][d], r split 4 x 9 ----
  {
    int l = tid & 63, q = tid >> 6;        // q in 0..3, rows q*9 .. q*9+8
    float acc[9] = {};
    for (int d = 0; d < 128; ++d) {
      float uv = us[l][d];
#pragma unroll
      for (int r = 0; r < 9; ++r) acc[r] += uv * xw[(q * 9 + r) * 128 + d];
    }
#pragma unroll
    for (int r = 0; r < 9; ++r) dbls[l][q * 9 + r] = acc[r];
  }
  __syncthreads();

  // ---- Phase C: delta = softplus(dt @ dtw^T + dtb), lanes along d ----
  {
    int d = tid & 127, lh = tid >> 7;
    const float4 wv = *reinterpret_cast<const float4*>(&dtw[d * 4]);
    float bv = dtb[d];
    float* dp = delta + ((size_t)n * L_ + l0 + lh * 32) * 128 + d;
    for (int l = 0; l < 32; ++l) {
      int lr = lh * 32 + l;
      float q0 = dbls[lr][0], q1 = dbls[lr][1], q2 = dbls[lr][2], q3 = dbls[lr][3];
      float dv = bv + q0 * wv.x + q1 * wv.y + q2 * wv.z + q3 * wv.w;
      dv = (dv > 20.f) ? dv : log1pf(__expf(dv));
      dp[(size_t)l * 128] = dv;
    }
  }

  // ---- Phase D: B/C stores (16-float runs per l) ----
  {
    int s = tid & 15;
    int which = (tid >> 4) & 1;            // 0 = B, 1 = C
    int lg = tid >> 5;                     // 0..7
    float* dst = which ? Cc : Bc;
    int roff = 4 + which * 16 + s;
    for (int l3 = lg; l3 < 64; l3 += 8) {
      dst[((size_t)n * L_ + l0 + l3) * 16 + s] = dbls[l3][roff];
    }
  }
}

// ---------------- K4a: per-chunk local scan (h from 0) + chunk delta-sum ----------------
__global__ __launch_bounds__(128) void k4a_chunk(
    const float* __restrict__ delta, const float* __restrict__ u,
    const float* __restrict__ Bc, const float* __restrict__ A_log,
    float* __restrict__ hend, float* __restrict__ Sdelta) {
  int c = blockIdx.x, n = blockIdx.y, d = threadIdx.x;
  __shared__ float Bs[CH * 16];
  const float* bsrc = Bc + ((size_t)n * L_ + c * CH) * 16;
  for (int e = d; e < CH * 16; e += 128) Bs[e] = bsrc[e];
  float A[16];
#pragma unroll
  for (int s = 0; s < 16; ++s) A[s] = -__expf(A_log[d * 16 + s]);
  __syncthreads();

  const float* dp = delta + ((size_t)n * L_ + c * CH) * 128 + d;
  const float* up = u + ((size_t)n * L_ + c * CH) * 128 + d;
  float h[16] = {};
  float sd = 0.f;
  float dv = dp[0], uv = up[0];
  for (int l = 0; l < CH; ++l) {
    int ln = (l + 1 < CH) ? l + 1 : l;
    float dvn = dp[(size_t)ln * 128];
    float uvn = up[(size_t)ln * 128];
    sd += dv;
    float du = dv * uv;
    float bsv[16];
    *reinterpret_cast<float4*>(&bsv[0])  = *reinterpret_cast<const float4*>(&Bs[l * 16 + 0]);
    *reinterpret_cast<float4*>(&bsv[4])  = *reinterpret_cast<const float4*>(&Bs[l * 16 + 4]);
    *reinterpret_cast<float4*>(&bsv[8])  = *reinterpret_cast<const float4*>(&Bs[l * 16 + 8]);
    *reinterpret_cast<float4*>(&bsv[12]) = *reinterpret_cast<const float4*>(&Bs[l * 16 + 12]);
#pragma unroll
    for (int s = 0; s < 16; ++s)
      h[s] = fmaf(__expf(dv * A[s]), h[s], du * bsv[s]);
    dv = dvn; uv = uvn;
  }
  float* hp = hend + (((size_t)n * NC + c) * 128 + d) * 16;
  *reinterpret_cast<float4*>(&hp[0])  = make_float4(h[0], h[1], h[2], h[3]);
  *reinterpret_cast<float4*>(&hp[4])  = make_float4(h[4], h[5], h[6], h[7]);
  *reinterpret_cast<float4*>(&hp[8])  = make_float4(h[8], h[9], h[10], h[11]);
  *reinterpret_cast<float4*>(&hp[12]) = make_float4(h[12], h[13], h[14], h[15]);
  Sdelta[((size_t)n * NC + c) * 128 + d] = sd;
}

// ---------------- K4b: cross-chunk combine (in-place hend -> Hstart prefix) ----------------
__global__ __launch_bounds__(256) void k4b_combine(
    const float* __restrict__ Sdelta, const float* __restrict__ A_log,
    float* __restrict__ hend) {
  int n = blockIdx.x >> 3, d0 = (blockIdx.x & 7) * 16;
  int d = d0 + (threadIdx.x >> 4), s = threadIdx.x & 15;
  float A = -__expf(A_log[d * 16 + s]);
  float H = 0.f;
  size_t i0 = ((size_t)n * NC) * 128 + d;
  float sd = Sdelta[i0];
  float he = hend[i0 * 16 + s];
  for (int c = 0; c < NC; ++c) {
    int cn = (c + 1 < NC) ? c + 1 : c;
    size_t in_ = ((size_t)n * NC + cn) * 128 + d;
    float sdn = Sdelta[in_];
    float hen = hend[in_ * 16 + s];
    size_t i = ((size_t)n * NC + c) * 128 + d;
    hend[i * 16 + s] = H;                    // store prefix (H before chunk c)
    H = fmaf(__expf(A * sd), H, he);
    sd = sdn; he = hen;
  }
}

// ---------------- K4c: per-chunk re-scan from Hstart, emit y ----------------
__global__ __launch_bounds__(128) void k4c_scan(
    const float* __restrict__ delta, const float* __restrict__ u,
    const float* __restrict__ Bc, const float* __restrict__ Cc,
    const float* __restrict__ A_log, const float* __restrict__ Hstart,
    float* __restrict__ y) {
  int c = blockIdx.x, n = blockIdx.y, d = threadIdx.x;
  __shared__ float Bs[CH * 16];
  __shared__ float Cs[CH * 16];
  const float* bsrc = Bc + ((size_t)n * L_ + c * CH) * 16;
  const float* csrc = Cc + ((size_t)n * L_ + c * CH) * 16;
  for (int e = d; e < CH * 16; e += 128) { Bs[e] = bsrc[e]; Cs[e] = csrc[e]; }
  float A[16];
#pragma unroll
  for (int s = 0; s < 16; ++s) A[s] = -__expf(A_log[d * 16 + s]);
  __syncthreads();

  const float* hp = Hstart + (((size_t)n * NC + c) * 128 + d) * 16;
  float h[16];
  *reinterpret_cast<float4*>(&h[0])  = *reinterpret_cast<const float4*>(&hp[0]);
  *reinterpret_cast<float4*>(&h[4])  = *reinterpret_cast<const float4*>(&hp[4]);
  *reinterpret_cast<float4*>(&h[8])  = *reinterpret_cast<const float4*>(&hp[8]);
  *reinterpret_cast<float4*>(&h[12]) = *reinterpret_cast<const float4*>(&hp[12]);

  const float* dp = delta + ((size_t)n * L_ + c * CH) * 128 + d;
  const float* up = u + ((size_t)n * L_ + c * CH) * 128 + d;
  float* yp = y + ((size_t)n * L_ + c * CH) * 128 + d;
  float dv = dp[0], uv = up[0];
  for (int l = 0; l < CH; ++l) {
    int ln = (l + 1 < CH) ? l + 1 : l;
    float dvn = dp[(size_t)ln * 128];
    float uvn = up[(size_t)ln * 128];
    float du = dv * uv;
    float bsv[16], csv[16];
    *reinterpret_cast<float4*>(&bsv[0])  = *reinterpret_cast<const float4*>(&Bs[l * 16 + 0]);
    *reinterpret_cast<float4*>(&bsv[4])  = *reinterpret_cast<const float4*>(&Bs[l * 16 + 4]);
    *reinterpret_cast<float4*>(&bsv[8])  = *reinterpret_cast<const float4*>(&Bs[l * 16 + 8]);
    *reinterpret_cast<float4*>(&bsv[12]) = *reinterpret_cast<const float4*>(&Bs[l * 16 + 12]);
    *reinterpret_cast<float4*>(&csv[0])  = *reinterpret_cast<const float4*>(&Cs[l * 16 + 0]);
    *reinterpret_cast<float4*>(&csv[4])  = *reinterpret_cast<const float4*>(&Cs[l * 16 + 4]);
    *reinterpret_cast<float4*>(&csv[8])  = *reinterpret_cast<const float4*>(&Cs[l * 16 + 8]);
    *reinterpret_cast<float4*>(&csv[12]) = *reinterpret_cast<const float4*>(&Cs[l * 16 + 12]);
    float yv = 0.f;
#pragma unroll
    for (int s = 0; s < 16; ++s) {
      h[s] = fmaf(__expf(dv * A[s]), h[s], du * bsv[s]);
      yv = fmaf(h[s], csv[s], yv);
    }
    yp[(size_t)l * 128] = yv;
    dv = dvn; uv = uvn;
  }
}

// ---------------- K5: gate + out_proj GEMM + skip ----------------
__global__ __launch_bounds__(256) void k5_gate_outproj(
    const float* __restrict__ y, const float* __restrict__ u,
    const float* __restrict__ z, const float* __restrict__ Dv,
    const float* __restrict__ ow, const float* __restrict__ stacked,
    const float* __restrict__ skip, float* __restrict__ ym) {
  int n = blockIdx.y, l0 = blockIdx.x * 64;
  __shared__ float As[64][132];
  __shared__ float Ws[64][132];
  int t = threadIdx.y * 16 + threadIdx.x;
  for (int e = t; e < 64 * 128; e += 256) {
    int r = e >> 7, c = e & 127;
    size_t idx = ((size_t)n * L_ + l0 + r) * 128 + c;
    float zz = z[idx];
    As[r][c] = (y[idx] + u[idx] * Dv[c]) * (zz / (1.f + __expf(-zz)));
    Ws[r][c] = ow[(size_t)r * 128 + c];
  }
  __syncthreads();
  float acc[4][4] = {};
  for (int jj = 0; jj < 32; ++jj) {
    float4 a[4], bm[4];
#pragma unroll
    for (int i = 0; i < 4; i++) a[i] = *reinterpret_cast<const float4*>(&As[threadIdx.y * 4 + i][jj * 4]);
#pragma unroll
    for (int i = 0; i < 4; i++) bm[i] = *reinterpret_cast<const float4*>(&Ws[threadIdx.x * 4 + i][jj * 4]);
#pragma unroll
    for (int i = 0; i < 4; i++)
#pragma unroll
      for (int kk = 0; kk < 4; kk++)
        acc[i][kk] += a[i].x * bm[kk].x + a[i].y * bm[kk].y + a[i].z * bm[kk].z + a[i].w * bm[kk].w;
  }
  float sk = skip[0];
#pragma unroll
  for (int i = 0; i < 4; i++) {
    int l = l0 + threadIdx.y * 4 + i;
    const float4 st = *reinterpret_cast<const float4*>(&stacked[((size_t)n * L_ + l) * 64 + threadIdx.x * 4]);
    float4 v = make_float4(acc[i][0] + sk * st.x, acc[i][1] + sk * st.y,
                           acc[i][2] + sk * st.z, acc[i][3] + sk * st.w);
    *reinterpret_cast<float4*>(&ym[((size_t)n * L_ + l) * 64 + threadIdx.x * 4]) = v;
  }
}

// ---------------- K6a: inverse shuffle + LayerNorm2 (wave per (b,l)) ----------------
__global__ __launch_bounds__(256) void k6a_ln2(
    const float* __restrict__ ym, const float* __restrict__ g,
    const float* __restrict__ bb, float* __restrict__ xmn) {
  int b = blockIdx.y;
  int l = blockIdx.x * 4 + (threadIdx.x >> 6);
  int j = threadIdx.x & 63;
  float v[4];
  float sum = 0.f, sq = 0.f;
#pragma unroll
  for (int br = 0; br < 4; ++br) {
    v[br] = ym[((size_t)(br * 4 + b) * L_ + l) * 64 + j];
    sum += v[br]; sq += v[br] * v[br];
  }
#pragma unroll
  for (int off = 1; off < 64; off <<= 1) {
    sum += __shfl_xor(sum, off);
    sq  += __shfl_xor(sq, off);
  }
  float mean = sum * (1.f / 256.f);
  float rstd = rsqrtf(sq * (1.f / 256.f) - mean * mean + 1e-5f);
#pragma unroll
  for (int br = 0; br < 4; ++br) {
    int c = (br * 64 + j + 224) & 255;
    xmn[((size_t)b * L_ + l) * 256 + c] = (v[br] - mean) * rstd * g[c] + bb[c];
  }
}

// ---------------- K6b: final 256x256 GEMM + bias, LDS-transposed coalesced store ----------------
__global__ __launch_bounds__(256) void k6b_proj(
    const float* __restrict__ xmn, const float* __restrict__ pw,
    const float* __restrict__ pb, float* __restrict__ out) {
  int b = blockIdx.z, k0 = blockIdx.y * 64, l0 = blockIdx.x * 64;
  __shared__ float As[64][68];
  __shared__ float Ws[64][68];
  int t = threadIdx.y * 16 + threadIdx.x;
  float acc[4][4] = {};
  for (int cc = 0; cc < 4; ++cc) {
    __syncthreads();
    for (int e = t; e < 4096; e += 256) {
      int r = e >> 6, c = e & 63;
      As[r][c] = xmn[((size_t)b * L_ + l0 + r) * 256 + cc * 64 + c];
      Ws[r][c] = pw[(k0 + r) * 256 + cc * 64 + c];
    }
    __syncthreads();
    for (int jj = 0; jj < 16; ++jj) {
      float4 a[4], bm[4];
#pragma unroll
      for (int i = 0; i < 4; i++) a[i] = *reinterpret_cast<const float4*>(&As[threadIdx.y * 4 + i][jj * 4]);
#pragma unroll
      for (int i = 0; i < 4; i++) bm[i] = *reinterpret_cast<const float4*>(&Ws[threadIdx.x * 4 + i][jj * 4]);
#pragma unroll
      for (int i = 0; i < 4; i++)
#pragma unroll
        for (int kk = 0; kk < 4; kk++)
          acc[i][kk] += a[i].x * bm[kk].x + a[i].y * bm[kk].y + a[i].z * bm[kk].z + a[i].w * bm[kk].w;
    }
  }
  __syncthreads();
  float* Ct = &As[0][0];
#pragma unroll
  for (int i = 0; i < 4; i++)
#pragma unroll
    for (int kk = 0; kk < 4; kk++)
      Ct[(threadIdx.y * 4 + i) * 65 + (threadIdx.x * 4 + kk)] = acc[i][kk];
  __syncthreads();
  int lane64 = t & 63, w = t >> 6;
#pragma unroll
  for (int p = 0; p < 16; ++p) {
    int row = p * 4 + w;
    out[((size_t)b * 256 + k0 + row) * L_ + l0 + lane64] = Ct[lane64 * 65 + row] + pb[k0 + row];
  }
}

extern "C" void kernel_launch(void* const* d_in, const int* in_sizes, int n_in,
                              void* d_out, int out_size, void* d_ws, size_t ws_size,
                              hipStream_t stream) {
  const float* x        = (const float*)d_in[0];
  const float* norm_g   = (const float*)d_in[1];
  const float* norm_b   = (const float*)d_in[2];
  const float* skip     = (const float*)d_in[3];
  const float* proj_w   = (const float*)d_in[4];
  const float* proj_b   = (const float*)d_in[5];
  const float* in_proj_w= (const float*)d_in[6];
  const float* conv_w   = (const float*)d_in[7];
  const float* conv_b   = (const float*)d_in[8];
  const float* x_proj_w = (const float*)d_in[9];
  const float* dt_w     = (const float*)d_in[10];
  const float* dt_b     = (const float*)d_in[11];
  const float* A_log    = (const float*)d_in[12];
  const float* Dv       = (const float*)d_in[13];
  const float* out_w    = (const float*)d_in[14];
  float* out = (float*)d_out;
  float* ws  = (float*)d_ws;

  // workspace layout (floats)
  float* stacked = ws;                    // 16*4096*64   = 4,194,304
  float* xi      = ws + 4194304;          // 16*4096*128  = 8,388,608  (reused as y after K4)
  float* z       = ws + 12582912;         // 8,388,608
  float* u       = ws + 20971520;         // 8,388,608
  float* delta   = ws + 29360128;         // 8,388,608   (reused: ym + xmn after K4)
  float* Bc      = ws + 37748736;         // 1,048,576
  float* Cc      = ws + 38797312;         // 1,048,576
  float* ym      = delta;                 // 4,194,304
  float* xmn     = delta + 4194304;       // 4,194,304

  // scan scratch lives in d_out (4M floats; fully overwritten by k6b at the end)
  float* hend   = out;                    // 16*64*128*16 = 2,097,152 (becomes Hstart in k4b)
  float* Sdelta = out + 2097152;          // 16*64*128    =   131,072

  k1_ln_scatter<<<dim3(64, 4), 256, 0, stream>>>(x, norm_g, norm_b, stacked);
  k2_inproj<<<dim3(64, 4, 16), dim3(16, 16), 0, stream>>>(stacked, in_proj_w, xi, z);
  k3_conv_xproj<<<dim3(64, 16), 256, 0, stream>>>(xi, conv_w, conv_b, x_proj_w,
                                                  dt_w, dt_b, u, delta, Bc, Cc);
  k4a_chunk<<<dim3(NC, 16), 128, 0, stream>>>(delta, u, Bc, A_log, hend, Sdelta);
  k4b_combine<<<128, 256, 0, stream>>>(Sdelta, A_log, hend);
  k4c_scan<<<dim3(NC, 16), 128, 0, stream>>>(delta, u, Bc, Cc, A_log, hend, xi /*y*/);
  k5_gate_outproj<<<dim3(64, 16), dim3(16, 16), 0, stream>>>(xi /*y*/, u, z, Dv,
                                                             out_w, stacked, skip, ym);
  k6a_ln2<<<dim3(1024, 4), 256, 0, stream>>>(ym, norm_g, norm_b, xmn);
  k6b_proj<<<dim3(64, 4, 4), dim3(16, 16), 0, stream>>>(xmn, proj_w, proj_b, out);
}